// Round 4
// baseline (1851.981 us; speedup 1.0000x reference)
//
#include <hip/hip_runtime.h>
#include <hip/hip_bf16.h>
#include <math.h>

// TemporalSkeletonBranch: 3-layer GCN (33 joints, 52->128->128->128) + temporal attention pool.
// Round 4: identical compute structure to R3 (per-tensor dtype detect + fp32 math),
// with ONE change: the output store is dtype-matched (fp32 unless inputs are bf16).
// Evidence: R2/R3's absmax was bit-identical to the stub's (1.9296875) <=> argmax|ref|
// in the half of d_out my bf16 stores never touched => d_out is fp32, values were right.

#define NJ 33
#define NF 52
#define NH 128
#define NT 256
#define NB 64
#define NSAMP (NB*NT)   // 16384

typedef unsigned short u16;

__device__ __forceinline__ float bf2f(u16 u) { return __uint_as_float(((unsigned)u) << 16); }
__device__ __forceinline__ float geluf(float v) {
    return 0.5f * v * (1.0f + erff(v * 0.70710678118654752440f));
}

// flag-based scalar load: f=1 -> buffer is bf16, f=0 -> fp32. Wave-uniform f.
__device__ __forceinline__ float ldv(const void* p, int i, int f) {
    float r;
    if (f) r = bf2f(((const u16*)p)[i]);
    else   r = ((const float*)p)[i];
    return r;
}

// dtype detector: scan the first 64 u16s. bf16 data (O(1) magnitudes) has ~100% of
// nonzero u16s with exponent-field in [0x40,0xBF]; fp32 read as u16 halves has ~50%
// mantissa-garbage halves -> ~75% in-band. Threshold 95%.
__device__ int detect_bf16(const void* p) {
    const u16* q = (const u16*)p;
    int nz = 0, ok = 0;
#pragma unroll
    for (int k = 0; k < 64; k++) {
        u16 u = q[k];
        if (u & 0x7FFF) {
            nz++;
            int e = (u >> 7) & 0xFF;
            ok += (e >= 0x40 && e <= 0xBF) ? 1 : 0;
        }
    }
    return (nz == 0) || (ok * 20 >= nz * 19);
}

// adjacency nonzero pattern (identity + BODY_EDGES both directions), 69 entries.
// constexpr so the scatter loop uses compile-time register indices (no scratch).
constexpr int NNZ = 69;
constexpr int ADJ_R[NNZ] = {
    0,0,0,0,0, 1, 2,2,2, 3, 4, 5,5,5, 6, 7,7,7, 8,8,8, 9, 10,
    11,11,11,11,11,11,11, 12,12,12,12,12,12,12,
    13,13,13, 14,14,14, 15,15, 16,16,
    17,18,19,20,21,22,
    23,23,23,23, 24,24,24,24,
    25,26,27,28,29,30,31,32 };
constexpr int ADJ_C[NNZ] = {
    0,2,5,11,12, 1, 0,2,7, 3, 4, 0,5,8, 6, 2,7,11, 5,8,12, 9, 10,
    0,7,11,12,13,23,24, 0,8,11,12,14,23,24,
    11,13,15, 12,14,16, 13,15, 14,16,
    17,18,19,20,21,22,
    11,12,23,24, 11,12,23,24,
    25,26,27,28,29,30,31,32 };

__global__ __launch_bounds__(256) void gcn_fused(
    const void* __restrict__ x,   const void* __restrict__ adj,
    const void* __restrict__ W0,  const void* __restrict__ b0,
    const void* __restrict__ S0,  const void* __restrict__ sb0,
    const void* __restrict__ g0,  const void* __restrict__ be0,
    const void* __restrict__ m0,  const void* __restrict__ v0,
    const void* __restrict__ W1,  const void* __restrict__ b1,
    const void* __restrict__ g1,  const void* __restrict__ be1,
    const void* __restrict__ m1,  const void* __restrict__ v1,
    const void* __restrict__ W2,  const void* __restrict__ b2,
    const void* __restrict__ g2,  const void* __restrict__ be2,
    const void* __restrict__ m2,  const void* __restrict__ v2,
    const void* __restrict__ tW1, const void* __restrict__ tb1,
    const void* __restrict__ tW2,
    float* __restrict__ xt_ws,    float* __restrict__ score_ws)
{
    __shared__ __align__(16) float xs[2][NJ][NF];     // 13.7 KB
    __shared__ __align__(16) float hbuf[2][NJ][NH];   // 33.8 KB
    __shared__ float adjv[NNZ];
    __shared__ __align__(16) float xtb[2][NH];
    __shared__ float rbuf[256];
    __shared__ int sflag[25];

    const int tid = threadIdx.x;
    const int si  = tid >> 7;        // which of the 2 samples in this block
    const int c   = tid & 127;       // hidden channel owned by this thread
    const int s   = blockIdx.x * 2 + si;

    // ---- per-tensor dtype detection: thread t handles tensor t; LDS broadcast ----
    if (tid < 25) {
        const void* p;
        switch (tid) {
            case 0:  p = x;   break;  case 1:  p = adj; break;
            case 2:  p = W0;  break;  case 3:  p = b0;  break;
            case 4:  p = S0;  break;  case 5:  p = sb0; break;
            case 6:  p = g0;  break;  case 7:  p = be0; break;
            case 8:  p = m0;  break;  case 9:  p = v0;  break;
            case 10: p = W1;  break;  case 11: p = b1;  break;
            case 12: p = g1;  break;  case 13: p = be1; break;
            case 14: p = m1;  break;  case 15: p = v1;  break;
            case 16: p = W2;  break;  case 17: p = b2;  break;
            case 18: p = g2;  break;  case 19: p = be2; break;
            case 20: p = m2;  break;  case 21: p = v2;  break;
            case 22: p = tW1; break;  case 23: p = tb1; break;
            default: p = tW2; break;
        }
        sflag[tid] = detect_bf16(p);
    }
    __syncthreads();
    const int fX   = sflag[0],  fADJ = sflag[1];
    const int fW0  = sflag[2],  fB0  = sflag[3],  fS0 = sflag[4],  fSB0 = sflag[5];
    const int fG0  = sflag[6],  fBE0 = sflag[7],  fM0 = sflag[8],  fV0  = sflag[9];
    const int fW1  = sflag[10], fB1  = sflag[11], fG1 = sflag[12], fBE1 = sflag[13];
    const int fM1  = sflag[14], fV1  = sflag[15];
    const int fW2  = sflag[16], fB2  = sflag[17], fG2 = sflag[18], fBE2 = sflag[19];
    const int fM2  = sflag[20], fV2  = sflag[21];
    const int fTW1 = sflag[22], fTB1 = sflag[23], fTW2 = sflag[24];

    // ---- stage x (both samples) into LDS, loop-level branch on dtype ----
    {
        float* xsf = &xs[0][0][0];
        if (fX) {
            const ushort4* xg = (const ushort4*)((const u16*)x + (size_t)blockIdx.x * 2 * NJ * NF);
            for (int i = tid; i < (2 * NJ * NF) / 4; i += 256) {
                ushort4 u = xg[i];
                float4 f; f.x = bf2f(u.x); f.y = bf2f(u.y); f.z = bf2f(u.z); f.w = bf2f(u.w);
                *(float4*)&xsf[4 * i] = f;
            }
        } else {
            const float4* xg = (const float4*)((const float*)x + (size_t)blockIdx.x * 2 * NJ * NF);
            for (int i = tid; i < (2 * NJ * NF) / 4; i += 256)
                *(float4*)&xsf[4 * i] = xg[i];
        }
    }
    if (tid < NNZ) adjv[tid] = ldv(adj, ADJ_R[tid] * NJ + ADJ_C[tid], fADJ);

    // ---- per-channel fused BN constants: y = z*A + D (D folds linear bias b) ----
    float A0, D0, A1, D1, A2, D2, sb0c, tb1c, tw2c;
    {
        float g = ldv(g0,c,fG0), be = ldv(be0,c,fBE0), m = ldv(m0,c,fM0), v = ldv(v0,c,fV0), b = ldv(b0,c,fB0);
        A0 = g * rsqrtf(v + 1e-5f); D0 = (b - m) * A0 + be;
        g = ldv(g1,c,fG1); be = ldv(be1,c,fBE1); m = ldv(m1,c,fM1); v = ldv(v1,c,fV1); b = ldv(b1,c,fB1);
        A1 = g * rsqrtf(v + 1e-5f); D1 = (b - m) * A1 + be;
        g = ldv(g2,c,fG2); be = ldv(be2,c,fBE2); m = ldv(m2,c,fM2); v = ldv(v2,c,fV2); b = ldv(b2,c,fB2);
        A2 = g * rsqrtf(v + 1e-5f); D2 = (b - m) * A2 + be;
        sb0c = ldv(sb0,c,fSB0); tb1c = ldv(tb1,c,fTB1); tw2c = ldv(tW2,c,fTW2);
    }
    __syncthreads();

    float hcol[NJ];   // this thread's column of h, carried across layers

    // ---------------- layer 0: z = adj@(x@W0), skip = x@S0 + sb0 ----------------
    {
        float acc[NJ], skp[NJ];
#pragma unroll
        for (int j = 0; j < NJ; j++) { acc[j] = 0.f; skp[j] = 0.f; }
#pragma unroll 1
        for (int k4 = 0; k4 < NF / 4; k4++) {
            float w0 = ldv(W0,(k4*4+0)*NH+c,fW0), w1 = ldv(W0,(k4*4+1)*NH+c,fW0);
            float w2 = ldv(W0,(k4*4+2)*NH+c,fW0), w3 = ldv(W0,(k4*4+3)*NH+c,fW0);
            float q0 = ldv(S0,(k4*4+0)*NH+c,fS0), q1 = ldv(S0,(k4*4+1)*NH+c,fS0);
            float q2 = ldv(S0,(k4*4+2)*NH+c,fS0), q3 = ldv(S0,(k4*4+3)*NH+c,fS0);
#pragma unroll
            for (int j = 0; j < NJ; j++) {
                float4 xv = *(const float4*)&xs[si][j][k4 * 4];
                acc[j] = fmaf(xv.x, w0, fmaf(xv.y, w1, fmaf(xv.z, w2, fmaf(xv.w, w3, acc[j]))));
                skp[j] = fmaf(xv.x, q0, fmaf(xv.y, q1, fmaf(xv.z, q2, fmaf(xv.w, q3, skp[j]))));
            }
        }
        float z[NJ];
#pragma unroll
        for (int j = 0; j < NJ; j++) z[j] = 0.f;
#pragma unroll
        for (int e = 0; e < NNZ; e++) z[ADJ_R[e]] += adjv[e] * acc[ADJ_C[e]];
#pragma unroll
        for (int j = 0; j < NJ; j++) hcol[j] = geluf(fmaf(z[j], A0, D0)) + skp[j] + sb0c;
    }

    // ---------------- layers 1 & 2: z = adj@(h@W); h = gelu(bn(z)) + h ----------------
    auto layer = [&](const void* __restrict__ W, int fW, float Al, float Dl) {
        __syncthreads();                       // previous readers of hbuf done
#pragma unroll
        for (int j = 0; j < NJ; j++) hbuf[si][j][c] = hcol[j];
        __syncthreads();
        float acc[NJ];
#pragma unroll
        for (int j = 0; j < NJ; j++) acc[j] = 0.f;
#pragma unroll 1
        for (int k4 = 0; k4 < NH / 4; k4++) {
            float w0 = ldv(W,(k4*4+0)*NH+c,fW), w1 = ldv(W,(k4*4+1)*NH+c,fW);
            float w2 = ldv(W,(k4*4+2)*NH+c,fW), w3 = ldv(W,(k4*4+3)*NH+c,fW);
#pragma unroll
            for (int j = 0; j < NJ; j++) {
                float4 hv = *(const float4*)&hbuf[si][j][k4 * 4];
                acc[j] = fmaf(hv.x, w0, fmaf(hv.y, w1, fmaf(hv.z, w2, fmaf(hv.w, w3, acc[j]))));
            }
        }
        float z[NJ];
#pragma unroll
        for (int j = 0; j < NJ; j++) z[j] = 0.f;
#pragma unroll
        for (int e = 0; e < NNZ; e++) z[ADJ_R[e]] += adjv[e] * acc[ADJ_C[e]];
#pragma unroll
        for (int j = 0; j < NJ; j++) hcol[j] += geluf(fmaf(z[j], Al, Dl));
    };
    layer(W1, fW1, A1, D1);
    layer(W2, fW2, A2, D2);

    // ---------------- mean over joints + attention score MLP ----------------
    float xtc = 0.f;
#pragma unroll
    for (int j = 0; j < NJ; j++) xtc += hcol[j];
    xtc *= (1.0f / 33.0f);
    xt_ws[(size_t)s * NH + c] = xtc;
    __syncthreads();                           // layer-2 GEMM reads of hbuf done
    xtb[si][c] = xtc;
    __syncthreads();

    float u = 0.f;
#pragma unroll 1
    for (int k4 = 0; k4 < NH / 4; k4++) {
        float w0 = ldv(tW1,(k4*4+0)*NH+c,fTW1), w1 = ldv(tW1,(k4*4+1)*NH+c,fTW1);
        float w2 = ldv(tW1,(k4*4+2)*NH+c,fTW1), w3 = ldv(tW1,(k4*4+3)*NH+c,fTW1);
        float4 xv = *(const float4*)&xtb[si][k4 * 4];
        u = fmaf(xv.x, w0, fmaf(xv.y, w1, fmaf(xv.z, w2, fmaf(xv.w, w3, u))));
    }
    // score contribution of this channel (tb2 omitted: softmax is shift-invariant)
    rbuf[tid] = geluf(u + tb1c) * tw2c;
    __syncthreads();
#pragma unroll
    for (int st = 64; st > 0; st >>= 1) {
        if (c < st) rbuf[tid] += rbuf[tid + st];
        __syncthreads();
    }
    if (c == 0) score_ws[s] = rbuf[si * 128];
}

// ---- kernel 2: softmax over T + attention-weighted sum -> out[B, H] ----
// Output dtype matches the dataset dtype (detected from x): fp32 unless bf16.
__global__ __launch_bounds__(256) void attn_pool(
    const void* __restrict__ x,
    const float* __restrict__ xt_ws, const float* __restrict__ score_ws,
    void* __restrict__ out)
{
    __shared__ float sc[NT];
    __shared__ float ew[NT];
    __shared__ float pb[256];
    __shared__ int sfx;
    const int tid = threadIdx.x, b = blockIdx.x;

    if (tid == 0) sfx = detect_bf16(x);
    sc[tid] = score_ws[b * NT + tid];
    __syncthreads();
    float mx = -1e30f;
#pragma unroll 8
    for (int i = 0; i < NT; i++) mx = fmaxf(mx, sc[i]);
    ew[tid] = expf(sc[tid] - mx);
    __syncthreads();
    float den = 0.f;
#pragma unroll 8
    for (int i = 0; i < NT; i++) den += ew[i];

    const int c = tid & 127, th = tid >> 7;
    float acc = 0.f;
    const float* xp = xt_ws + ((size_t)b * NT + th * 128) * NH + c;
#pragma unroll 4
    for (int i = 0; i < 128; i++) acc = fmaf(ew[th * 128 + i], xp[(size_t)i * NH], acc);
    pb[tid] = acc;
    __syncthreads();
    if (tid < NH) {
        float r = (pb[tid] + pb[tid + 128]) / den;
        if (sfx) ((__hip_bfloat16*)out)[b * NH + tid] = __float2bfloat16(r);
        else     ((float*)out)[b * NH + tid] = r;
    }
}

extern "C" void kernel_launch(void* const* d_in, const int* in_sizes, int n_in,
                              void* d_out, int out_size, void* d_ws, size_t ws_size,
                              hipStream_t stream) {
    // d_ws layout (floats): xt[NSAMP*NH], scores[NSAMP]  (8.45 MB total)
    float* xt_ws    = (float*)d_ws;
    float* score_ws = xt_ws + (size_t)NSAMP * NH;

    gcn_fused<<<NSAMP / 2, 256, 0, stream>>>(
        d_in[0], d_in[1], d_in[2], d_in[3], d_in[4], d_in[5], d_in[6], d_in[7],
        d_in[8], d_in[9], d_in[10], d_in[11], d_in[12], d_in[13], d_in[14], d_in[15],
        d_in[16], d_in[17], d_in[18], d_in[19], d_in[20], d_in[21], d_in[22], d_in[23],
        d_in[24], xt_ws, score_ws);
    attn_pool<<<NB, 256, 0, stream>>>(d_in[0], xt_ws, score_ws, d_out);
}